// Round 8
// baseline (393.690 us; speedup 1.0000x reference)
//
#include <hip/hip_runtime.h>

// VQEmbedding forward (TRAINING=True):
//   z_e_x [32,256,64,64] f32, codebook [512,256] f32, labels [32] i32
//   out = concat(z_q_x, z_q_x_bar), each [32,256,64,64] f32 — both equal
//   codebook[argmin] in the forward pass (x+(c-x) roundoff ~4e-7 << thr).
//
// Reference arithmetic emulated bit-exactly:
//   - dot: ascending-d fp32 FMA chain per (point, code)  (== sgemm)
//   - in_sqr: fp64 ascending-d fma -> fp32
//   - cb_sqr: fp64 LDS tree -> fp32
//   - dist = fmaf(-2, acc, fl(insq + cbs_k)); strict < ascending k == first tie
//
// Ladder: R0 structure (4 waves/64 pts/13 codes, SGPR cb operands) vq ~146;
// +NT stores (R7) total 397.7; +PF=8 pipeline (R9) total 393.4 (vq ~133).
// Restructures measured WORSE: R5 8-wave/2pt: 201; R6 LDS-staged: 338.
//
// R10/R11: split vq at the argmin seam (fidx = 1 int/point, 0.5 MB in ws):
//   A argmin_kernel — identical compute loop, epilogue -> 256 B fidx store.
//   B emit_kernel   — pure streaming: int4 fidx load, 4 L1 gathers/row,
//                     two dwordx4 NT stores/row, 100% occupancy, no deps.
// (R11 = R10 with compile fix: __builtin_nontemporal_store needs a clang
//  ext_vector_type, not HIP_vector_type<float,4>.)

#define D       256
#define KCODES  512
#define HW      4096
#define BATCH   32
#define NPTS    (BATCH * HW)   // 131072
#define WPW     13             // codes per wave (4*13=52 >= max class size 51)
#define PF      8              // prefetch depth (d-steps in flight)

typedef float fx4 __attribute__((ext_vector_type(4)));

__constant__ int c_cls_start[11] = {0, 51, 101, 151, 201, 251, 301, 352, 402, 452, 502};

// Prep: cbT[d][k] = cb[k][d]  (per-d class slice contiguous -> scalar loads),
//       cbs[k] = fl32( fp64 sum_d cb[k][d]^2 )
__global__ __launch_bounds__(256) void prep_kernel(const float* __restrict__ cb,
                                                   float* __restrict__ cbT,
                                                   float* __restrict__ cbs) {
    const int k = blockIdx.x;   // 0..511
    const int d = threadIdx.x;  // 0..255
    float v = cb[k * D + d];
    cbT[(size_t)d * KCODES + k] = v;
    __shared__ double red[256];
    red[d] = (double)v * (double)v;
    __syncthreads();
    for (int s = 128; s > 0; s >>= 1) {
        if (d < s) red[d] += red[d + s];
        __syncthreads();
    }
    if (d == 0) cbs[k] = (float)red[0];
}

__global__ __launch_bounds__(256, 8) void argmin_kernel(const float* __restrict__ z,
                                                        const int* __restrict__ labels,
                                                        const float* __restrict__ cbT,
                                                        const float* __restrict__ cbs,
                                                        int* __restrict__ fidxg) {
    const int lane = threadIdx.x & 63;
    const int w    = __builtin_amdgcn_readfirstlane(threadIdx.x >> 6);  // wave id 0..3
    const int b    = blockIdx.x >> 6;                  // 64 blocks per image
    const int hw   = ((blockIdx.x & 63) << 6) | lane;  // this lane's point
    const int lab  = __builtin_amdgcn_readfirstlane(labels[b]);
    const int c0   = c_cls_start[lab];
    const int cnt  = c_cls_start[lab + 1] - c0;        // 50 or 51
    const int kbase = c0 + w * WPW;                    // wave-uniform (SGPR)
    const int myn   = min(WPW, cnt - w * WPW);         // 13,13,13,{11|12}

    const float* __restrict__ xp = z + (size_t)b * (D * HW) + hw;  // x[d] = xp[d*HW]

    float acc[WPW];
#pragma unroll
    for (int j = 0; j < WPW; ++j) acc[j] = 0.0f;

    double xsq = 0.0;  // ||x||^2 in fp64, ascending d

    // x software pipeline, depth 8 (two 4-d groups in flight)
    float xb[PF];
#pragma unroll
    for (int i = 0; i < PF; ++i) xb[i] = xp[(size_t)i * HW];

    for (int d = 0; d < D; d += PF) {
        float xn[PF];
#pragma unroll
        for (int i = 0; i < PF; ++i) {
            int dn = (d + PF + i) & (D - 1);  // wrap on last chunk (harmless reload)
            xn[i] = xp[(size_t)dn * HW];
        }
#pragma unroll
        for (int i = 0; i < PF; ++i) {
            // wave-uniform address -> scalar loads, SGPR FMA operand
            const float* __restrict__ wd = cbT + (size_t)(d + i) * KCODES + kbase;
            const float x = xb[i];
            xsq = fma((double)x, (double)x, xsq);
#pragma unroll
            for (int j = 0; j < WPW; ++j)
                acc[j] = fmaf(x, wd[j], acc[j]);  // ascending-d fp32 chain == sgemm
        }
#pragma unroll
        for (int i = 0; i < PF; ++i) xb[i] = xn[i];
    }

    // Emulated reference distance; local argmin over this wave's codes
    const float insq = (float)xsq;
    float best = __builtin_inff();
    int bi = kbase;
#pragma unroll
    for (int j = 0; j < WPW; ++j) {
        if (j < myn) {
            float T    = insq + cbs[kbase + j];    // fp32 add, RNE
            float dist = fmaf(-2.0f, acc[j], T);   // == fl(T - 2*acc)
            if (dist < best) { best = dist; bi = kbase + j; }
        }
    }

    // Cross-wave argmin via LDS (ascending w + strict < == lowest-index tie-break)
    __shared__ float sd[4][64];
    __shared__ int   si[4][64];
    sd[w][lane] = best;
    si[w][lane] = bi;
    __syncthreads();
    if (w == 0) {
        float fb = sd[0][lane];
        int   fi = si[0][lane];
#pragma unroll
        for (int w2 = 1; w2 < 4; ++w2) {
            float dv = sd[w2][lane];
            if (dv < fb) { fb = dv; fi = si[w2][lane]; }
        }
        fidxg[(size_t)b * HW + hw] = fi;   // 256 B coalesced per block
    }
}

// Pure streaming emit: out0 = out1 = cbT[d][fidx]. Lane owns 4 consecutive
// points (one int4 fidx load); wave covers 16 d-rows; per row: 4 gathers in a
// ~204 B class window (L1) + two dwordx4 NT stores (coalesced 1 KB/wave).
__global__ __launch_bounds__(256) void emit_kernel(const int* __restrict__ fidxg,
                                                   const float* __restrict__ cbT,
                                                   float* __restrict__ out) {
    const int lane = threadIdx.x & 63;
    const int w    = threadIdx.x >> 6;       // 0..3
    const int s    = blockIdx.x >> 2;        // point-slice 0..511
    const int dq   = blockIdx.x & 3;         // d-quarter 0..3
    const int b    = s >> 4;                 // 16 slices per image
    const int p0   = ((s & 15) << 8) | (lane << 2);   // 4 consecutive points

    const int4 f = *(const int4*)(fidxg + (size_t)b * HW + p0);

    float* __restrict__ o0 = out + (size_t)b * (D * HW) + p0;
    float* __restrict__ o1 = o0 + (size_t)NPTS * D;
    const int d0 = (dq << 6) | (w << 4);     // 16 rows per wave
    const float* __restrict__ row = cbT + (size_t)d0 * KCODES;
#pragma unroll 4
    for (int d = d0; d < d0 + 16; ++d) {
        fx4 v;
        v.x = row[f.x];
        v.y = row[f.y];
        v.z = row[f.z];
        v.w = row[f.w];
        __builtin_nontemporal_store(v, (fx4*)(o0 + (size_t)d * HW));
        __builtin_nontemporal_store(v, (fx4*)(o1 + (size_t)d * HW));
        row += KCODES;
    }
}

extern "C" void kernel_launch(void* const* d_in, const int* in_sizes, int n_in,
                              void* d_out, int out_size, void* d_ws, size_t ws_size,
                              hipStream_t stream) {
    const float* z      = (const float*)d_in[0];
    const float* cb     = (const float*)d_in[1];
    const int*   labels = (const int*)d_in[2];
    float* out = (float*)d_out;

    float* cbT  = (float*)d_ws;               // 256*512 f32 = 512 KB
    float* cbs  = cbT + (size_t)D * KCODES;   // 512 f32 (2 KB)
    int*   fidx = (int*)(cbs + KCODES);       // 131072 i32 = 512 KB

    hipLaunchKernelGGL(prep_kernel, dim3(KCODES), dim3(D), 0, stream, cb, cbT, cbs);
    hipLaunchKernelGGL(argmin_kernel, dim3(NPTS / 64), dim3(256), 0, stream,
                       z, labels, cbT, cbs, fidx);
    hipLaunchKernelGGL(emit_kernel, dim3((NPTS / 256) * 4), dim3(256), 0, stream,
                       fidx, cbT, out);
}